// Round 12
// baseline (366.599 us; speedup 1.0000x reference)
//
#include <hip/hip_runtime.h>

#define NNODE 50000
#define NEDGE 800000
#define DIM   128
#define NEG   0.2f
#define NBUCK 196
#define EPB1  2048
#define NB1   391
#define GBLK  782          // ceil(NNODE/64)
#define MSTR  136          // LDS M-row stride in shorts (128 + 8 pad)

typedef __attribute__((ext_vector_type(8))) short bf16x8;
typedef __attribute__((ext_vector_type(4))) float f32x4;

__device__ __forceinline__ float wmax(float v){
  #pragma unroll
  for (int m = 32; m > 0; m >>= 1) v = fmaxf(v, __shfl_xor(v, m));
  return v;
}
__device__ __forceinline__ float wsum(float v){
  #pragma unroll
  for (int m = 32; m > 0; m >>= 1) v += __shfl_xor(v, m);
  return v;
}
__device__ __forceinline__ unsigned short f2bf(float f){
  unsigned int x = __float_as_uint(f);
  return (unsigned short)((x + 0x7fffu + ((x >> 16) & 1u)) >> 16);
}
__device__ __forceinline__ float bflo(unsigned u){ return __uint_as_float(u << 16); }
__device__ __forceinline__ float bfhi(unsigned u){ return __uint_as_float(u & 0xffff0000u); }

// ---------------- CSR build: radix-style, NO global atomics ----------------
__global__ __launch_bounds__(256) void bhist2_k(const int* __restrict__ dst,
                                                int* __restrict__ cnt){
  __shared__ int h[NBUCK];
  for (int i = threadIdx.x; i < NBUCK; i += 256) h[i] = 0;
  __syncthreads();
  int e0 = blockIdx.x * EPB1 + threadIdx.x;
  #pragma unroll
  for (int i = 0; i < 8; ++i){
    int e = e0 + i * 256;
    if (e < NEDGE) atomicAdd(&h[dst[e] >> 8], 1);
  }
  __syncthreads();
  for (int i = threadIdx.x; i < NBUCK; i += 256)
    cnt[i * NB1 + blockIdx.x] = h[i];
}

__global__ __launch_bounds__(256) void scan196_k(const int* __restrict__ cnt,
                                                 int* __restrict__ cbase,
                                                 int* __restrict__ btot){
  __shared__ int sd[256];
  int b = blockIdx.x, t = threadIdx.x;
  const int* row = cnt + (size_t)b * NB1;
  int i0 = t * 2, i1 = t * 2 + 1;
  int v0 = (i0 < NB1) ? row[i0] : 0;
  int v1 = (i1 < NB1) ? row[i1] : 0;
  int s = v0 + v1;
  sd[t] = s; __syncthreads();
  #pragma unroll
  for (int off = 1; off < 256; off <<= 1){
    int u = (t >= off) ? sd[t - off] : 0;
    __syncthreads();
    sd[t] += u;
    __syncthreads();
  }
  int ex = sd[t] - s;
  if (i0 < NB1) cbase[(size_t)b * NB1 + i0] = ex;
  if (i1 < NB1) cbase[(size_t)b * NB1 + i1] = ex + v0;
  if (t == 255) btot[b] = sd[255];
}

__global__ __launch_bounds__(256) void bscan2_k(const int* __restrict__ btot,
                                                int* __restrict__ gbase,
                                                int* __restrict__ rp){
  __shared__ int sd[256];
  int t = threadIdx.x;
  int v = (t < NBUCK) ? btot[t] : 0;
  sd[t] = v; __syncthreads();
  #pragma unroll
  for (int off = 1; off < 256; off <<= 1){
    int u = (t >= off) ? sd[t - off] : 0;
    __syncthreads();
    sd[t] += u;
    __syncthreads();
  }
  if (t < NBUCK) gbase[t] = sd[t] - v;
  if (t == NBUCK - 1) gbase[NBUCK] = sd[t];
  if (t == 0) rp[NNODE] = NEDGE;
}

__global__ __launch_bounds__(256) void scat2_k(const int* __restrict__ ei,
                                               const int* __restrict__ gbase,
                                               const int* __restrict__ cbase,
                                               unsigned int* __restrict__ packed){
  __shared__ int lcur[NBUCK];
  for (int i = threadIdx.x; i < NBUCK; i += 256) lcur[i] = 0;
  __syncthreads();
  int e0 = blockIdx.x * EPB1 + threadIdx.x;
  #pragma unroll
  for (int i = 0; i < 8; ++i){
    int e = e0 + i * 256;
    if (e < NEDGE){
      int s = ei[e], d = ei[NEDGE + e];
      int b = d >> 8;
      int r = atomicAdd(&lcur[b], 1);
      int pos = gbase[b] + cbase[(size_t)b * NB1 + blockIdx.x] + r;
      packed[pos] = ((unsigned)d << 16) | (unsigned)s;
    }
  }
}

__global__ __launch_bounds__(256) void build_k(const int* __restrict__ gbase,
                                               const unsigned int* __restrict__ packed,
                                               int* __restrict__ rp,
                                               unsigned short* __restrict__ es){
  __shared__ int h[256], sd[256], cur[256];
  int b = blockIdx.x, t = threadIdx.x;
  int s0 = gbase[b], s1 = gbase[b + 1];
  h[t] = 0; __syncthreads();
  for (int i = s0 + t; i < s1; i += 256)
    atomicAdd(&h[(packed[i] >> 16) & 255], 1);
  __syncthreads();
  int v = h[t]; sd[t] = v; __syncthreads();
  #pragma unroll
  for (int off = 1; off < 256; off <<= 1){
    int u = (t >= off) ? sd[t - off] : 0;
    __syncthreads();
    sd[t] += u;
    __syncthreads();
  }
  int ex = sd[t] - v;
  cur[t] = ex;
  int d = b * 256 + t;
  if (d < NNODE) rp[d] = s0 + ex;
  __syncthreads();
  for (int i = s0 + t; i < s1; i += 256){
    unsigned int p = packed[i];
    int ld = (p >> 16) & 255;
    int pos = atomicAdd(&cur[ld], 1);
    es[s0 + pos] = (unsigned short)(p & 0xffffu);
  }
}

// ------- prepA: swizzle Wf1=[w0s;wl0], Wf2=[w1;wl1] (256x128) -> B-frag bf16 -------
__global__ __launch_bounds__(256) void prepA_k(const float* __restrict__ w0s,
                                               const float* __restrict__ wl0,
                                               const float* __restrict__ w1,
                                               const float* __restrict__ wl1,
                                               unsigned short* __restrict__ Wz1,
                                               unsigned short* __restrict__ Wz2){
  int g = blockIdx.x * 256 + threadIdx.x;    // 0..8191
  int layer = g >> 12;
  int rem = g & 4095;
  int ct = rem >> 9, q = (rem >> 6) & 7, lane = rem & 63;
  int quad = lane >> 4;
  int c = ct * 16 + (lane & 15);
  const float* wA = layer ? w1 : w0s;
  const float* wB = layer ? wl1 : wl0;
  unsigned short* dst = (layer ? Wz2 : Wz1) + ((size_t)(ct * 8 + q) * 64 + lane) * 8;
  #pragma unroll
  for (int j = 0; j < 8; ++j){
    int k = q * 32 + quad * 8 + j;
    float v = (k < 128) ? wA[k * 128 + c] : wB[(k - 128) * 128 + c];
    dst[j] = f2bf(v);
  }
}

// ------- prepH: Wf3 = [w2;wl2]@wh (256x64) swizzled bf16; block 8: bf3 -------
__global__ __launch_bounds__(256) void prepH_k(const float* __restrict__ w2,
                                               const float* __restrict__ wl2,
                                               const float* __restrict__ wh,
                                               const float* __restrict__ bc2,
                                               const float* __restrict__ bl2,
                                               const float* __restrict__ bh,
                                               unsigned short* __restrict__ Wz3,
                                               float* __restrict__ bf3){
  if (blockIdx.x == 8){
    int c = threadIdx.x;
    if (c < 64){
      float s = bh[c];
      for (int t = 0; t < 128; ++t) s += (bc2[t] + bl2[t]) * wh[t * 64 + c];
      bf3[c] = s;
    }
    return;
  }
  int g = blockIdx.x * 256 + threadIdx.x;    // 0..2047
  int ct = g >> 9, q = (g >> 6) & 7, lane = g & 63;
  int quad = lane >> 4;
  int c = ct * 16 + (lane & 15);             // < 64
  unsigned short* dst = Wz3 + ((size_t)(ct * 8 + q) * 64 + lane) * 8;
  #pragma unroll
  for (int j = 0; j < 8; ++j){
    int k = q * 32 + quad * 8 + j;
    const float* src = (k < 128) ? (w2 + k * 128) : (wl2 + (k - 128) * 128);
    float s = 0.f;
    for (int t = 0; t < 128; ++t) s += src[t] * wh[t * 64 + c];
    dst[j] = f2bf(s);
  }
}

// ------- mv6 + fused biases -------
__global__ void mv6_k(const float* __restrict__ w0s, const float* __restrict__ a0s,
                      const float* __restrict__ w0d, const float* __restrict__ a0d,
                      const float* __restrict__ w1,  const float* __restrict__ a1s,
                      const float* __restrict__ a1d,
                      const float* __restrict__ w2,  const float* __restrict__ a2s,
                      const float* __restrict__ a2d,
                      const float* __restrict__ bc0, const float* __restrict__ bl0,
                      const float* __restrict__ bc1, const float* __restrict__ bl1,
                      float* __restrict__ uv,        // 6*128: u0 v0 u1 v1 u2 v2
                      float* __restrict__ bf1, float* __restrict__ bf2){
  if (blockIdx.x == 192){
    int t = threadIdx.x;
    if (t < 128) bf1[t] = bc0[t] + bl0[t];
    else bf2[t - 128] = bc1[t - 128] + bl1[t - 128];
    return;
  }
  int lane = threadIdx.x & 63;
  int idx = blockIdx.x * 4 + (threadIdx.x >> 6);   // 0..767
  int grp = idx >> 7, r = idx & 127;
  const float* W; const float* a;
  switch (grp){
    case 0: W = w0s; a = a0s; break;
    case 1: W = w0d; a = a0d; break;
    case 2: W = w1;  a = a1s; break;
    case 3: W = w1;  a = a1d; break;
    case 4: W = w2;  a = a2s; break;
    default: W = w2; a = a2d; break;
  }
  float2 w = ((const float2*)(W + r * DIM))[lane];
  float2 av = ((const float2*)a)[lane];
  float s = wsum(w.x * av.x + w.y * av.y);
  if (lane == 0) uv[grp * 128 + r] = s;
}

// ------- cvt + layer-0 logits: Xb = bf16(x); als/ald = x@u0, x@v0 -------
__global__ __launch_bounds__(256) void cvtdual_k(const float* __restrict__ X,
                                                 const float* __restrict__ uv,
                                                 unsigned int* __restrict__ Xb,
                                                 float* __restrict__ als,
                                                 float* __restrict__ ald){
  int lane = threadIdx.x & 63;
  int n = blockIdx.x * 4 + (threadIdx.x >> 6);
  if (n >= NNODE) return;
  float2 xv = ((const float2*)(X + (size_t)n * DIM))[lane];
  Xb[(size_t)n * 64 + lane] = (unsigned)f2bf(xv.x) | ((unsigned)f2bf(xv.y) << 16);
  float2 uu = ((const float2*)uv)[lane];
  float2 vv = ((const float2*)(uv + 128))[lane];
  float s1 = wsum(xv.x * uu.x + xv.y * uu.y);
  float s2 = wsum(xv.x * vv.x + xv.y * vv.y);
  if (lane == 0){ als[n] = s1; ald[n] = s2; }
}

// ------- fused GAT + K=256 MFMA per 64-row block --------------------------
// Phase A: per-wave softmax-gather of 16 nodes -> M rows in LDS (bf16).
// Phase B: out = [M | Hg] @ Wz + bias;  FINAL=0: relu, bf16 Hout + logits;
//          FINAL=1: f32 out (64 cols), no relu.
template<int FINAL>
__global__ __launch_bounds__(256) void gm_k(const int* __restrict__ rp,
                                            const unsigned short* __restrict__ es,
                                            const float* __restrict__ als_in,
                                            const float* __restrict__ ald_in,
                                            const unsigned int* __restrict__ Hg,
                                            const unsigned short* __restrict__ Wz,
                                            const float* __restrict__ bias,
                                            const float* __restrict__ u,
                                            const float* __restrict__ v,
                                            unsigned short* __restrict__ Hout,
                                            float* __restrict__ outf,
                                            float* __restrict__ als_out,
                                            float* __restrict__ ald_out){
  __shared__ unsigned short Ms[64 * MSTR + 8];
  int lane = threadIdx.x & 63;
  int wave = threadIdx.x >> 6;
  int r0w  = blockIdx.x * 64 + wave * 16;

  // ---- Phase A: gather 16 nodes per wave ----
  for (int i = 0; i < 16; ++i){
    int n = r0w + i;
    float2 acc = make_float2(0.f, 0.f);
    float rinv = 0.f;
    if (n < NNODE){
      int start = rp[n], end = rp[n + 1];
      int deg = end - start;
      float ad = ald_in[n];
      if (deg <= 64){
        int s = 0; float z = -3.0e38f;
        if (lane < deg){
          s = es[start + lane];
          float t = als_in[s] + ad;
          z = t > 0.f ? t : NEG * t;
        }
        float m = wmax(z);
        float e = (lane < deg) ? __expf(z - m) : 0.f;
        float denom = wsum(e);
        rinv = (deg > 0) ? 1.f / denom : 0.f;
        int dq = (deg + 7) & ~7;
        for (int j = 0; j < dq; j += 8){
          int   s0 = __shfl(s, j),     s1 = __shfl(s, j + 1);
          int   s2 = __shfl(s, j + 2), s3 = __shfl(s, j + 3);
          int   s4 = __shfl(s, j + 4), s5 = __shfl(s, j + 5);
          int   s6 = __shfl(s, j + 6), s7 = __shfl(s, j + 7);
          float w0 = __shfl(e, j),     w1 = __shfl(e, j + 1);
          float w2 = __shfl(e, j + 2), w3 = __shfl(e, j + 3);
          float w4 = __shfl(e, j + 4), w5 = __shfl(e, j + 5);
          float w6 = __shfl(e, j + 6), w7 = __shfl(e, j + 7);
          unsigned p0 = Hg[(size_t)s0 * 64 + lane];
          unsigned p1 = Hg[(size_t)s1 * 64 + lane];
          unsigned p2 = Hg[(size_t)s2 * 64 + lane];
          unsigned p3 = Hg[(size_t)s3 * 64 + lane];
          unsigned p4 = Hg[(size_t)s4 * 64 + lane];
          unsigned p5 = Hg[(size_t)s5 * 64 + lane];
          unsigned p6 = Hg[(size_t)s6 * 64 + lane];
          unsigned p7 = Hg[(size_t)s7 * 64 + lane];
          acc.x = fmaf(w0, bflo(p0), acc.x); acc.y = fmaf(w0, bfhi(p0), acc.y);
          acc.x = fmaf(w1, bflo(p1), acc.x); acc.y = fmaf(w1, bfhi(p1), acc.y);
          acc.x = fmaf(w2, bflo(p2), acc.x); acc.y = fmaf(w2, bfhi(p2), acc.y);
          acc.x = fmaf(w3, bflo(p3), acc.x); acc.y = fmaf(w3, bfhi(p3), acc.y);
          acc.x = fmaf(w4, bflo(p4), acc.x); acc.y = fmaf(w4, bfhi(p4), acc.y);
          acc.x = fmaf(w5, bflo(p5), acc.x); acc.y = fmaf(w5, bfhi(p5), acc.y);
          acc.x = fmaf(w6, bflo(p6), acc.x); acc.y = fmaf(w6, bfhi(p6), acc.y);
          acc.x = fmaf(w7, bflo(p7), acc.x); acc.y = fmaf(w7, bfhi(p7), acc.y);
        }
      } else {
        float mloc = -3.0e38f;
        for (int ii = start + lane; ii < end; ii += 64){
          int s = es[ii];
          float zz = als_in[s] + ad;
          zz = zz > 0.f ? zz : NEG * zz;
          mloc = fmaxf(mloc, zz);
        }
        float m = wmax(mloc);
        float dloc = 0.f;
        for (int ii = start + lane; ii < end; ii += 64){
          int s = es[ii];
          float zz = als_in[s] + ad;
          zz = zz > 0.f ? zz : NEG * zz;
          dloc += __expf(zz - m);
        }
        rinv = 1.f / wsum(dloc);
        for (int ii = start; ii < end; ++ii){
          int s = es[ii];
          float zz = als_in[s] + ad;
          zz = zz > 0.f ? zz : NEG * zz;
          float w = __expf(zz - m);
          unsigned p = Hg[(size_t)s * 64 + lane];
          acc.x = fmaf(w, bflo(p), acc.x);
          acc.y = fmaf(w, bfhi(p), acc.y);
        }
      }
    }
    int nl = wave * 16 + i;
    *(unsigned*)&Ms[nl * MSTR + lane * 2] =
        (unsigned)f2bf(acc.x * rinv) | ((unsigned)f2bf(acc.y * rinv) << 16);
  }
  __syncthreads();

  // ---- Phase B: [M | Hg-rows] @ Wz ----
  int quad = lane >> 4;
  int col  = lane & 15;
  int rA = r0w + col; if (rA > NNODE - 1) rA = NNODE - 1;
  const bf16x8* hrow = (const bf16x8*)(Hg + (size_t)rA * 64);
  bf16x8 a[8];
  #pragma unroll
  for (int q = 0; q < 4; ++q){
    a[q]     = *(const bf16x8*)&Ms[(wave * 16 + col) * MSTR + q * 32 + quad * 8];
    a[q + 4] = hrow[q * 4 + quad];
  }

  const bf16x8* wz = (const bf16x8*)Wz;
  int rowq = r0w + quad * 4;
  float alsp[4] = {0.f, 0.f, 0.f, 0.f};
  float aldp[4] = {0.f, 0.f, 0.f, 0.f};
  const int NCT = FINAL ? 4 : 8;

  #pragma unroll
  for (int ct = 0; ct < NCT; ++ct){
    f32x4 acc = {0.f, 0.f, 0.f, 0.f};
    #pragma unroll
    for (int q = 0; q < 8; ++q){
      bf16x8 bfr = wz[(ct * 8 + q) * 64 + lane];
      acc = __builtin_amdgcn_mfma_f32_16x16x32_bf16(a[q], bfr, acc, 0, 0, 0);
    }
    int c = ct * 16 + col;
    float bb = bias[c];
    if (FINAL){
      #pragma unroll
      for (int r = 0; r < 4; ++r){
        int row = rowq + r;
        if (row < NNODE) outf[(size_t)row * 64 + c] = acc[r] + bb;
      }
    } else {
      float uc = u[c], vc = v[c];
      #pragma unroll
      for (int r = 0; r < 4; ++r){
        float h = fmaxf(acc[r] + bb, 0.f);
        alsp[r] = fmaf(h, uc, alsp[r]);
        aldp[r] = fmaf(h, vc, aldp[r]);
        int row = rowq + r;
        if (row < NNODE) Hout[(size_t)row * 128 + c] = f2bf(h);
      }
    }
  }

  if (!FINAL){
    #pragma unroll
    for (int m = 1; m < 16; m <<= 1){
      #pragma unroll
      for (int r = 0; r < 4; ++r){
        alsp[r] += __shfl_xor(alsp[r], m);
        aldp[r] += __shfl_xor(aldp[r], m);
      }
    }
    if (col == 0){
      #pragma unroll
      for (int r = 0; r < 4; ++r){
        int row = rowq + r;
        if (row < NNODE){ als_out[row] = alsp[r]; ald_out[row] = aldp[r]; }
      }
    }
  }
}

extern "C" void kernel_launch(void* const* d_in, const int* in_sizes, int n_in,
                              void* d_out, int out_size, void* d_ws, size_t ws_size,
                              hipStream_t stream){
  const float* x   = (const float*)d_in[0];
  const int*   ei  = (const int*)d_in[1];
  const float* w0s = (const float*)d_in[2];
  const float* w0d = (const float*)d_in[3];
  const float* a0s = (const float*)d_in[4];
  const float* a0d = (const float*)d_in[5];
  const float* bc0 = (const float*)d_in[6];
  const float* wl0 = (const float*)d_in[7];
  const float* bl0 = (const float*)d_in[8];
  const float* w1  = (const float*)d_in[9];
  const float* a1s = (const float*)d_in[10];
  const float* a1d = (const float*)d_in[11];
  const float* bc1 = (const float*)d_in[12];
  const float* wl1 = (const float*)d_in[13];
  const float* bl1 = (const float*)d_in[14];
  const float* w2  = (const float*)d_in[15];
  const float* a2s = (const float*)d_in[16];
  const float* a2d = (const float*)d_in[17];
  const float* bc2 = (const float*)d_in[18];
  const float* wl2 = (const float*)d_in[19];
  const float* bl2 = (const float*)d_in[20];
  const float* wh  = (const float*)d_in[21];
  const float* bh  = (const float*)d_in[22];
  float* out = (float*)d_out;

  unsigned int* Xb = (unsigned int*)d_ws;                        // [N,128] bf16
  unsigned int* Ha = Xb + (size_t)NNODE * 64;                    // [N,128] bf16
  unsigned int* Hb = Ha + (size_t)NNODE * 64;                    // [N,128] bf16
  float* alsA = (float*)(Hb + (size_t)NNODE * 64);
  float* aldA = alsA + NNODE;
  float* alsB = aldA + NNODE;
  float* aldB = alsB + NNODE;
  float* uv   = aldB + NNODE;                // 6*128
  float* bf1  = uv + 6 * 128;                // 128
  float* bf2  = bf1 + 128;                   // 128
  float* bf3  = bf2 + 128;                   // 64
  unsigned short* Wz1 = (unsigned short*)(bf3 + 64);             // 256*128
  unsigned short* Wz2 = Wz1 + 256 * 128;                         // 256*128
  unsigned short* Wz3 = Wz2 + 256 * 128;                         // 256*64
  int*   rp    = (int*)(Wz3 + 256 * 64);     // NNODE+1
  int*   cnt   = rp + (NNODE + 1);           // NBUCK*NB1
  int*   cbase = cnt + NBUCK * NB1;          // NBUCK*NB1
  int*   btot  = cbase + NBUCK * NB1;        // NBUCK
  int*   gbase = btot + NBUCK;               // NBUCK+1
  unsigned int* packed = (unsigned int*)(gbase + (NBUCK + 1));   // NEDGE
  unsigned short* es   = (unsigned short*)(packed + NEDGE);      // NEDGE

  // ---- CSR by dst: radix-style, zero global atomics ----
  bhist2_k<<<NB1, 256, 0, stream>>>(ei + NEDGE, cnt);
  scan196_k<<<NBUCK, 256, 0, stream>>>(cnt, cbase, btot);
  bscan2_k<<<1, 256, 0, stream>>>(btot, gbase, rp);
  scat2_k<<<NB1, 256, 0, stream>>>(ei, gbase, cbase, packed);
  build_k<<<NBUCK, 256, 0, stream>>>(gbase, packed, rp, es);

  dim3 b(256);
  dim3 gn((NNODE + 3) / 4);

  // ---- prep: fused weights, logit vectors, fused biases ----
  prepA_k<<<32, b, 0, stream>>>(w0s, wl0, w1, wl1, Wz1, Wz2);
  prepH_k<<<9, b, 0, stream>>>(w2, wl2, wh, bc2, bl2, bh, Wz3, bf3);
  mv6_k<<<193, b, 0, stream>>>(w0s, a0s, w0d, a0d, w1, a1s, a1d, w2, a2s, a2d,
                               bc0, bl0, bc1, bl1, uv, bf1, bf2);
  cvtdual_k<<<gn, b, 0, stream>>>(x, uv, Xb, alsA, aldA);

  // ---- layer 0: gather x, h1 = relu([M0|x]@Wf1 + bf1), logits1 -> B ----
  gm_k<0><<<GBLK, b, 0, stream>>>(rp, es, alsA, aldA, Xb, Wz1, bf1,
                                  uv + 2 * 128, uv + 3 * 128,
                                  (unsigned short*)Ha, nullptr, alsB, aldB);

  // ---- layer 1: gather h1, h2 = relu([M1|h1]@Wf2 + bf2), logits2 -> A ----
  gm_k<0><<<GBLK, b, 0, stream>>>(rp, es, alsB, aldB, Ha, Wz2, bf2,
                                  uv + 4 * 128, uv + 5 * 128,
                                  (unsigned short*)Hb, nullptr, alsA, aldA);

  // ---- layer 2 + head: gather h2, out = [M2|h2]@Wf3 + bf3 ----
  gm_k<1><<<GBLK, b, 0, stream>>>(rp, es, alsA, aldA, Hb, Wz3, bf3,
                                  nullptr, nullptr, nullptr, out,
                                  nullptr, nullptr);
}

// Round 13
// 316.648 us; speedup vs baseline: 1.1578x; 1.1578x over previous
//
#include <hip/hip_runtime.h>

#define NNODE 50000
#define NEDGE 800000
#define DIM   128
#define NEG   0.2f
#define NBUCK 196
#define EPB1  2048
#define NB1   391
#define GBLK  782          // ceil(NNODE/64)
#define GN    12500        // ceil(NNODE/4) node-blocks (4 waves of 1 node)
#define SB_PA (NB1)        // setup_k block ranges
#define SB_PH (SB_PA + 32)
#define SB_MV (SB_PH + 9)
#define SB_CV (SB_MV + 193)
#define SB_TOT (SB_CV + GN)

typedef __attribute__((ext_vector_type(8))) short bf16x8;
typedef __attribute__((ext_vector_type(4))) float f32x4;

__device__ __forceinline__ float wmax(float v){
  #pragma unroll
  for (int m = 32; m > 0; m >>= 1) v = fmaxf(v, __shfl_xor(v, m));
  return v;
}
__device__ __forceinline__ float wsum(float v){
  #pragma unroll
  for (int m = 32; m > 0; m >>= 1) v += __shfl_xor(v, m);
  return v;
}
__device__ __forceinline__ unsigned short f2bf(float f){
  unsigned int x = __float_as_uint(f);
  return (unsigned short)((x + 0x7fffu + ((x >> 16) & 1u)) >> 16);
}
__device__ __forceinline__ float bflo(unsigned u){ return __uint_as_float(u << 16); }
__device__ __forceinline__ float bfhi(unsigned u){ return __uint_as_float(u & 0xffff0000u); }

// ---- setup_k: bhist2 | prepA | prepH | mv6 | cvtdual (independent, one launch) ----
__global__ __launch_bounds__(256) void setup_k(
    const int* __restrict__ ei,
    const float* __restrict__ x,
    const float* __restrict__ w0s, const float* __restrict__ a0s,
    const float* __restrict__ w0d, const float* __restrict__ a0d,
    const float* __restrict__ bc0, const float* __restrict__ wl0,
    const float* __restrict__ bl0,
    const float* __restrict__ w1,  const float* __restrict__ a1s,
    const float* __restrict__ a1d, const float* __restrict__ bc1,
    const float* __restrict__ wl1, const float* __restrict__ bl1,
    const float* __restrict__ w2,  const float* __restrict__ a2s,
    const float* __restrict__ a2d, const float* __restrict__ bc2,
    const float* __restrict__ wl2, const float* __restrict__ bl2,
    const float* __restrict__ wh,  const float* __restrict__ bh,
    int* __restrict__ cnt,
    unsigned short* __restrict__ Wz1, unsigned short* __restrict__ Wz2,
    unsigned short* __restrict__ Wz3, float* __restrict__ bf3,
    float* __restrict__ uv, float* __restrict__ bf1, float* __restrict__ bf2,
    unsigned int* __restrict__ Xb, float* __restrict__ als, float* __restrict__ ald){
  int bid = blockIdx.x;

  if (bid < NB1){                       // ---- bhist2 ----
    __shared__ int h[NBUCK];
    const int* dst = ei + NEDGE;
    for (int i = threadIdx.x; i < NBUCK; i += 256) h[i] = 0;
    __syncthreads();
    int e0 = bid * EPB1 + threadIdx.x;
    #pragma unroll
    for (int i = 0; i < 8; ++i){
      int e = e0 + i * 256;
      if (e < NEDGE) atomicAdd(&h[dst[e] >> 8], 1);
    }
    __syncthreads();
    for (int i = threadIdx.x; i < NBUCK; i += 256)
      cnt[i * NB1 + bid] = h[i];
    return;
  }
  if (bid < SB_PH){                     // ---- prepA ----
    int g = (bid - SB_PA) * 256 + threadIdx.x;   // 0..8191
    int layer = g >> 12;
    int rem = g & 4095;
    int ct = rem >> 9, q = (rem >> 6) & 7, lane = rem & 63;
    int quad = lane >> 4;
    int c = ct * 16 + (lane & 15);
    const float* wA = layer ? w1 : w0s;
    const float* wB = layer ? wl1 : wl0;
    unsigned short* dst = (layer ? Wz2 : Wz1) + ((size_t)(ct * 8 + q) * 64 + lane) * 8;
    #pragma unroll
    for (int j = 0; j < 8; ++j){
      int k = q * 32 + quad * 8 + j;
      float v = (k < 128) ? wA[k * 128 + c] : wB[(k - 128) * 128 + c];
      dst[j] = f2bf(v);
    }
    return;
  }
  if (bid < SB_MV){                     // ---- prepH ----
    int pb = bid - SB_PH;
    if (pb == 8){
      int c = threadIdx.x;
      if (c < 64){
        float s = bh[c];
        for (int t = 0; t < 128; ++t) s += (bc2[t] + bl2[t]) * wh[t * 64 + c];
        bf3[c] = s;
      }
      return;
    }
    int g = pb * 256 + threadIdx.x;     // 0..2047
    int ct = g >> 9, q = (g >> 6) & 7, lane = g & 63;
    int quad = lane >> 4;
    int c = ct * 16 + (lane & 15);      // < 64
    unsigned short* dst = Wz3 + ((size_t)(ct * 8 + q) * 64 + lane) * 8;
    #pragma unroll
    for (int j = 0; j < 8; ++j){
      int k = q * 32 + quad * 8 + j;
      const float* src = (k < 128) ? (w2 + k * 128) : (wl2 + (k - 128) * 128);
      float s = 0.f;
      for (int t = 0; t < 128; ++t) s += src[t] * wh[t * 64 + c];
      dst[j] = f2bf(s);
    }
    return;
  }
  if (bid < SB_CV){                     // ---- mv6 + fused biases ----
    int mb = bid - SB_MV;
    if (mb == 192){
      int t = threadIdx.x;
      if (t < 128) bf1[t] = bc0[t] + bl0[t];
      else bf2[t - 128] = bc1[t - 128] + bl1[t - 128];
      return;
    }
    int lane = threadIdx.x & 63;
    int idx = mb * 4 + (threadIdx.x >> 6);   // 0..767
    int grp = idx >> 7, r = idx & 127;
    const float* W; const float* a;
    switch (grp){
      case 0: W = w0s; a = a0s; break;
      case 1: W = w0d; a = a0d; break;
      case 2: W = w1;  a = a1s; break;
      case 3: W = w1;  a = a1d; break;
      case 4: W = w2;  a = a2s; break;
      default: W = w2; a = a2d; break;
    }
    float2 w = ((const float2*)(W + r * DIM))[lane];
    float2 av = ((const float2*)a)[lane];
    float s = wsum(w.x * av.x + w.y * av.y);
    if (lane == 0) uv[grp * 128 + r] = s;
    return;
  }
  {                                     // ---- cvtdual ----
    int lane = threadIdx.x & 63;
    int n = (bid - SB_CV) * 4 + (threadIdx.x >> 6);
    if (n >= NNODE) return;
    float2 xv = ((const float2*)(x + (size_t)n * DIM))[lane];
    Xb[(size_t)n * 64 + lane] = (unsigned)f2bf(xv.x) | ((unsigned)f2bf(xv.y) << 16);
    float2 uu = ((const float2*)uv)[lane];
    float2 vv = ((const float2*)(uv + 128))[lane];
    float s1 = wsum(xv.x * uu.x + xv.y * uu.y);
    float s2 = wsum(xv.x * vv.x + xv.y * vv.y);
    if (lane == 0){ als[n] = s1; ald[n] = s2; }
  }
}

// NOTE: cvtdual reads uv written by mv6 *in the same launch* — different blocks,
// no ordering guarantee! Fix: cvtdual computes its own dots directly from
// (w0s,a0s),(w0d,a0d)? That costs a 128x128 matvec per node — no. Instead we
// keep logits exact by computing als/ald from x via u,v — so u,v MUST be ready.
// => mv6's grp 0/1 results are needed. To keep one launch correct, cvtdual
// recomputes u,v per wave? Too expensive. SOLUTION: layer-0 logits use the
// identity als = x @ (w0s@a0s): each cvtdual wave computes dot(x_n, u) with u
// loaded from global — written by mv6 blocks that may not have run yet. UNSAFE.
// Therefore: cvtdual does NOT read uv. It computes s1 = dot(x_n@?) — cannot.
// => keep logits out of setup_k: gat0 reads als/ald produced by a tiny dual_k
// launched after setup_k. (See dual_k below; 12500 blocks, ~4 us.)

__global__ __launch_bounds__(256) void dual_k(const float* __restrict__ X,
                                              const float* __restrict__ uv,
                                              float* __restrict__ als,
                                              float* __restrict__ ald){
  int lane = threadIdx.x & 63;
  int n = blockIdx.x * 4 + (threadIdx.x >> 6);
  if (n >= NNODE) return;
  float2 xv = ((const float2*)(X + (size_t)n * DIM))[lane];
  float2 uu = ((const float2*)uv)[lane];
  float2 vv = ((const float2*)(uv + 128))[lane];
  float s1 = wsum(xv.x * uu.x + xv.y * uu.y);
  float s2 = wsum(xv.x * vv.x + xv.y * vv.y);
  if (lane == 0){ als[n] = s1; ald[n] = s2; }
}

// ---------------- CSR build: radix-style, NO global atomics ----------------
__global__ __launch_bounds__(256) void scan196_k(const int* __restrict__ cnt,
                                                 int* __restrict__ cbase,
                                                 int* __restrict__ btot){
  __shared__ int sd[256];
  int b = blockIdx.x, t = threadIdx.x;
  const int* row = cnt + (size_t)b * NB1;
  int i0 = t * 2, i1 = t * 2 + 1;
  int v0 = (i0 < NB1) ? row[i0] : 0;
  int v1 = (i1 < NB1) ? row[i1] : 0;
  int s = v0 + v1;
  sd[t] = s; __syncthreads();
  #pragma unroll
  for (int off = 1; off < 256; off <<= 1){
    int u = (t >= off) ? sd[t - off] : 0;
    __syncthreads();
    sd[t] += u;
    __syncthreads();
  }
  int ex = sd[t] - s;
  if (i0 < NB1) cbase[(size_t)b * NB1 + i0] = ex;
  if (i1 < NB1) cbase[(size_t)b * NB1 + i1] = ex + v0;
  if (t == 255) btot[b] = sd[255];
}

__global__ __launch_bounds__(256) void bscan2_k(const int* __restrict__ btot,
                                                int* __restrict__ gbase,
                                                int* __restrict__ rp){
  __shared__ int sd[256];
  int t = threadIdx.x;
  int v = (t < NBUCK) ? btot[t] : 0;
  sd[t] = v; __syncthreads();
  #pragma unroll
  for (int off = 1; off < 256; off <<= 1){
    int u = (t >= off) ? sd[t - off] : 0;
    __syncthreads();
    sd[t] += u;
    __syncthreads();
  }
  if (t < NBUCK) gbase[t] = sd[t] - v;
  if (t == NBUCK - 1) gbase[NBUCK] = sd[t];
  if (t == 0) rp[NNODE] = NEDGE;
}

__global__ __launch_bounds__(256) void scat2_k(const int* __restrict__ ei,
                                               const int* __restrict__ gbase,
                                               const int* __restrict__ cbase,
                                               unsigned int* __restrict__ packed){
  __shared__ int lcur[NBUCK];
  for (int i = threadIdx.x; i < NBUCK; i += 256) lcur[i] = 0;
  __syncthreads();
  int e0 = blockIdx.x * EPB1 + threadIdx.x;
  #pragma unroll
  for (int i = 0; i < 8; ++i){
    int e = e0 + i * 256;
    if (e < NEDGE){
      int s = ei[e], d = ei[NEDGE + e];
      int b = d >> 8;
      int r = atomicAdd(&lcur[b], 1);
      int pos = gbase[b] + cbase[(size_t)b * NB1 + blockIdx.x] + r;
      packed[pos] = ((unsigned)d << 16) | (unsigned)s;
    }
  }
}

__global__ __launch_bounds__(256) void build_k(const int* __restrict__ gbase,
                                               const unsigned int* __restrict__ packed,
                                               int* __restrict__ rp,
                                               unsigned short* __restrict__ es){
  __shared__ int h[256], sd[256], cur[256];
  int b = blockIdx.x, t = threadIdx.x;
  int s0 = gbase[b], s1 = gbase[b + 1];
  h[t] = 0; __syncthreads();
  for (int i = s0 + t; i < s1; i += 256)
    atomicAdd(&h[(packed[i] >> 16) & 255], 1);
  __syncthreads();
  int v = h[t]; sd[t] = v; __syncthreads();
  #pragma unroll
  for (int off = 1; off < 256; off <<= 1){
    int u = (t >= off) ? sd[t - off] : 0;
    __syncthreads();
    sd[t] += u;
    __syncthreads();
  }
  int ex = sd[t] - v;
  cur[t] = ex;
  int d = b * 256 + t;
  if (d < NNODE) rp[d] = s0 + ex;
  __syncthreads();
  for (int i = s0 + t; i < s1; i += 256){
    unsigned int p = packed[i];
    int ld = (p >> 16) & 255;
    int pos = atomicAdd(&cur[ld], 1);
    es[s0 + pos] = (unsigned short)(p & 0xffffu);
  }
}

// ---------------- GAT: Mb[n] = softmax-weighted sum of Hg rows (bf16) ----------------
__global__ __launch_bounds__(256) void gat_k(const int* __restrict__ rp,
                                             const unsigned short* __restrict__ es,
                                             const float* __restrict__ als,
                                             const float* __restrict__ ald,
                                             const unsigned int* __restrict__ A,
                                             unsigned int* __restrict__ Mb){
  int lane = threadIdx.x & 63;
  int n = blockIdx.x * 4 + (threadIdx.x >> 6);
  if (n >= NNODE) return;
  int start = rp[n], end = rp[n + 1];
  int deg = end - start;
  float ad = ald[n];
  float2 acc = make_float2(0.f, 0.f);
  float rinv = 0.f;

  if (deg <= 64){
    int s = 0; float z = -3.0e38f;
    if (lane < deg){
      s = es[start + lane];
      float t = als[s] + ad;
      z = t > 0.f ? t : NEG * t;
    }
    float m = wmax(z);
    float e = (lane < deg) ? __expf(z - m) : 0.f;
    float denom = wsum(e);
    rinv = (deg > 0) ? 1.f / denom : 0.f;
    int dq = (deg + 7) & ~7;
    for (int j = 0; j < dq; j += 8){
      int   s0 = __shfl(s, j),     s1 = __shfl(s, j + 1);
      int   s2 = __shfl(s, j + 2), s3 = __shfl(s, j + 3);
      int   s4 = __shfl(s, j + 4), s5 = __shfl(s, j + 5);
      int   s6 = __shfl(s, j + 6), s7 = __shfl(s, j + 7);
      float w0 = __shfl(e, j),     w1 = __shfl(e, j + 1);
      float w2 = __shfl(e, j + 2), w3 = __shfl(e, j + 3);
      float w4 = __shfl(e, j + 4), w5 = __shfl(e, j + 5);
      float w6 = __shfl(e, j + 6), w7 = __shfl(e, j + 7);
      unsigned p0 = A[(size_t)s0 * 64 + lane];
      unsigned p1 = A[(size_t)s1 * 64 + lane];
      unsigned p2 = A[(size_t)s2 * 64 + lane];
      unsigned p3 = A[(size_t)s3 * 64 + lane];
      unsigned p4 = A[(size_t)s4 * 64 + lane];
      unsigned p5 = A[(size_t)s5 * 64 + lane];
      unsigned p6 = A[(size_t)s6 * 64 + lane];
      unsigned p7 = A[(size_t)s7 * 64 + lane];
      acc.x = fmaf(w0, bflo(p0), acc.x); acc.y = fmaf(w0, bfhi(p0), acc.y);
      acc.x = fmaf(w1, bflo(p1), acc.x); acc.y = fmaf(w1, bfhi(p1), acc.y);
      acc.x = fmaf(w2, bflo(p2), acc.x); acc.y = fmaf(w2, bfhi(p2), acc.y);
      acc.x = fmaf(w3, bflo(p3), acc.x); acc.y = fmaf(w3, bfhi(p3), acc.y);
      acc.x = fmaf(w4, bflo(p4), acc.x); acc.y = fmaf(w4, bfhi(p4), acc.y);
      acc.x = fmaf(w5, bflo(p5), acc.x); acc.y = fmaf(w5, bfhi(p5), acc.y);
      acc.x = fmaf(w6, bflo(p6), acc.x); acc.y = fmaf(w6, bfhi(p6), acc.y);
      acc.x = fmaf(w7, bflo(p7), acc.x); acc.y = fmaf(w7, bfhi(p7), acc.y);
    }
  } else {
    float mloc = -3.0e38f;
    for (int i = start + lane; i < end; i += 64){
      int s = es[i];
      float zz = als[s] + ad;
      zz = zz > 0.f ? zz : NEG * zz;
      mloc = fmaxf(mloc, zz);
    }
    float m = wmax(mloc);
    float dloc = 0.f;
    for (int i = start + lane; i < end; i += 64){
      int s = es[i];
      float zz = als[s] + ad;
      zz = zz > 0.f ? zz : NEG * zz;
      dloc += __expf(zz - m);
    }
    rinv = 1.f / wsum(dloc);
    for (int i = start; i < end; ++i){
      int s = es[i];
      float zz = als[s] + ad;
      zz = zz > 0.f ? zz : NEG * zz;
      float w = __expf(zz - m);
      unsigned p = A[(size_t)s * 64 + lane];
      acc.x = fmaf(w, bflo(p), acc.x);
      acc.y = fmaf(w, bfhi(p), acc.y);
    }
  }

  Mb[(size_t)n * 64 + lane] =
      (unsigned)f2bf(acc.x * rinv) | ((unsigned)f2bf(acc.y * rinv) << 16);
}

// ------- K=256 fused MFMA: out = [Mb | Hin] @ Wz + bias ------------------
template<int FINAL>
__global__ __launch_bounds__(256) void mfma_k(const unsigned int* __restrict__ Mb,
                                              const unsigned int* __restrict__ Hin,
                                              const unsigned short* __restrict__ Wz,
                                              const float* __restrict__ bias,
                                              const float* __restrict__ u,
                                              const float* __restrict__ v,
                                              unsigned short* __restrict__ Hout,
                                              float* __restrict__ outf,
                                              float* __restrict__ als,
                                              float* __restrict__ ald){
  int lane = threadIdx.x & 63;
  int wid  = threadIdx.x >> 6;
  int r0   = blockIdx.x * 64 + wid * 16;
  int quad = lane >> 4;
  int col  = lane & 15;

  int rA = r0 + col; if (rA > NNODE - 1) rA = NNODE - 1;
  const bf16x8* mrow = (const bf16x8*)(Mb + (size_t)rA * 64);
  const bf16x8* hrow = (const bf16x8*)(Hin + (size_t)rA * 64);
  bf16x8 a[8];
  #pragma unroll
  for (int q = 0; q < 4; ++q){
    a[q]     = mrow[q * 4 + quad];
    a[q + 4] = hrow[q * 4 + quad];
  }

  const bf16x8* wz = (const bf16x8*)Wz;
  int rowq = r0 + quad * 4;
  float alsp[4] = {0.f, 0.f, 0.f, 0.f};
  float aldp[4] = {0.f, 0.f, 0.f, 0.f};
  const int NCT = FINAL ? 4 : 8;

  #pragma unroll
  for (int ct = 0; ct < NCT; ++ct){
    f32x4 acc = {0.f, 0.f, 0.f, 0.f};
    #pragma unroll
    for (int q = 0; q < 8; ++q){
      bf16x8 bfr = wz[(ct * 8 + q) * 64 + lane];
      acc = __builtin_amdgcn_mfma_f32_16x16x32_bf16(a[q], bfr, acc, 0, 0, 0);
    }
    int c = ct * 16 + col;
    float bb = bias[c];
    if (FINAL){
      #pragma unroll
      for (int r = 0; r < 4; ++r){
        int row = rowq + r;
        if (row < NNODE) outf[(size_t)row * 64 + c] = acc[r] + bb;
      }
    } else {
      float uc = u[c], vc = v[c];
      #pragma unroll
      for (int r = 0; r < 4; ++r){
        float h = fmaxf(acc[r] + bb, 0.f);
        alsp[r] = fmaf(h, uc, alsp[r]);
        aldp[r] = fmaf(h, vc, aldp[r]);
        int row = rowq + r;
        if (row < NNODE) Hout[(size_t)row * 128 + c] = f2bf(h);
      }
    }
  }

  if (!FINAL){
    #pragma unroll
    for (int m = 1; m < 16; m <<= 1){
      #pragma unroll
      for (int r = 0; r < 4; ++r){
        alsp[r] += __shfl_xor(alsp[r], m);
        aldp[r] += __shfl_xor(aldp[r], m);
      }
    }
    if (col == 0){
      #pragma unroll
      for (int r = 0; r < 4; ++r){
        int row = rowq + r;
        if (row < NNODE){ als[row] = alsp[r]; ald[row] = aldp[r]; }
      }
    }
  }
}

extern "C" void kernel_launch(void* const* d_in, const int* in_sizes, int n_in,
                              void* d_out, int out_size, void* d_ws, size_t ws_size,
                              hipStream_t stream){
  const float* x   = (const float*)d_in[0];
  const int*   ei  = (const int*)d_in[1];
  const float* w0s = (const float*)d_in[2];
  const float* w0d = (const float*)d_in[3];
  const float* a0s = (const float*)d_in[4];
  const float* a0d = (const float*)d_in[5];
  const float* bc0 = (const float*)d_in[6];
  const float* wl0 = (const float*)d_in[7];
  const float* bl0 = (const float*)d_in[8];
  const float* w1  = (const float*)d_in[9];
  const float* a1s = (const float*)d_in[10];
  const float* a1d = (const float*)d_in[11];
  const float* bc1 = (const float*)d_in[12];
  const float* wl1 = (const float*)d_in[13];
  const float* bl1 = (const float*)d_in[14];
  const float* w2  = (const float*)d_in[15];
  const float* a2s = (const float*)d_in[16];
  const float* a2d = (const float*)d_in[17];
  const float* bc2 = (const float*)d_in[18];
  const float* wl2 = (const float*)d_in[19];
  const float* bl2 = (const float*)d_in[20];
  const float* wh  = (const float*)d_in[21];
  const float* bh  = (const float*)d_in[22];
  float* out = (float*)d_out;

  unsigned int* Xb = (unsigned int*)d_ws;                        // [N,128] bf16
  unsigned int* Ha = Xb + (size_t)NNODE * 64;                    // [N,128] bf16
  unsigned int* Hb = Ha + (size_t)NNODE * 64;                    // [N,128] bf16
  unsigned int* Mb = Hb + (size_t)NNODE * 64;                    // [N,128] bf16
  float* alsA = (float*)(Mb + (size_t)NNODE * 64);
  float* aldA = alsA + NNODE;
  float* alsB = aldA + NNODE;
  float* aldB = alsB + NNODE;
  float* uv   = aldB + NNODE;                // 6*128
  float* bf1  = uv + 6 * 128;                // 128
  float* bf2  = bf1 + 128;                   // 128
  float* bf3  = bf2 + 128;                   // 64
  unsigned short* Wz1 = (unsigned short*)(bf3 + 64);             // 256*128
  unsigned short* Wz2 = Wz1 + 256 * 128;                         // 256*128
  unsigned short* Wz3 = Wz2 + 256 * 128;                         // 256*64
  int*   rp    = (int*)(Wz3 + 256 * 64);     // NNODE+1
  int*   cnt   = rp + (NNODE + 1);           // NBUCK*NB1
  int*   cbase = cnt + NBUCK * NB1;          // NBUCK*NB1
  int*   btot  = cbase + NBUCK * NB1;        // NBUCK
  int*   gbase = btot + NBUCK;               // NBUCK+1
  unsigned int* packed = (unsigned int*)(gbase + (NBUCK + 1));   // NEDGE
  unsigned short* es   = (unsigned short*)(packed + NEDGE);      // NEDGE

  dim3 b(256);
  dim3 gn(GN);

  // ---- setup: bhist2 + weight swizzles + matvecs + x->bf16 (one launch) ----
  setup_k<<<SB_TOT, b, 0, stream>>>(ei, x,
      w0s, a0s, w0d, a0d, bc0, wl0, bl0,
      w1, a1s, a1d, bc1, wl1, bl1,
      w2, a2s, a2d, bc2, wl2, bl2, wh, bh,
      cnt, Wz1, Wz2, Wz3, bf3, uv, bf1, bf2, Xb, alsA, aldA);

  // ---- layer-0 logits (needs uv from setup_k) ----
  dual_k<<<gn, b, 0, stream>>>(x, uv, alsA, aldA);

  // ---- CSR: scan + scatter + per-bucket build ----
  scan196_k<<<NBUCK, b, 0, stream>>>(cnt, cbase, btot);
  bscan2_k<<<1, b, 0, stream>>>(btot, gbase, rp);
  scat2_k<<<NB1, b, 0, stream>>>(ei, gbase, cbase, packed);
  build_k<<<NBUCK, b, 0, stream>>>(gbase, packed, rp, es);

  // ---- layer 0: gather x -> M0; h1 = relu([M0|x]@Wf1 + bf1); logits1 -> B ----
  gat_k<<<gn, b, 0, stream>>>(rp, es, alsA, aldA, Xb, Mb);
  mfma_k<0><<<GBLK, b, 0, stream>>>(Mb, Xb, Wz1, bf1, uv + 2 * 128, uv + 3 * 128,
                                    (unsigned short*)Ha, nullptr, alsB, aldB);

  // ---- layer 1 ----
  gat_k<<<gn, b, 0, stream>>>(rp, es, alsB, aldB, Ha, Mb);
  mfma_k<0><<<GBLK, b, 0, stream>>>(Mb, Ha, Wz2, bf2, uv + 4 * 128, uv + 5 * 128,
                                    (unsigned short*)Hb, nullptr, alsA, aldA);

  // ---- layer 2 + head ----
  gat_k<<<gn, b, 0, stream>>>(rp, es, alsA, aldA, Hb, Mb);
  mfma_k<1><<<GBLK, b, 0, stream>>>(Mb, Hb, Wz3, bf3, nullptr, nullptr,
                                    nullptr, out, nullptr, nullptr);
}